// Round 1
// baseline (278.345 us; speedup 1.0000x reference)
//
#include <hip/hip_runtime.h>
#include <hip/hip_bf16.h>
#include <math.h>

#define POST 128
#define NI 129            // T+1
#define NJK 4225          // 65*65
#define KPAD 4288         // 67*64
#define NTOT 16512        // 129*128
#define KBLKS 134         // KPAD/32
#define MBLKS 32          // 512/16

typedef __attribute__((ext_vector_type(8))) short bf16x8;
typedef __attribute__((ext_vector_type(4))) float f32x4;

__device__ __forceinline__ unsigned short f2bf(float f){
    unsigned u = __builtin_bit_cast(unsigned, f);
    unsigned r = (u + 0x7FFFu + ((u >> 16) & 1u)) >> 16;   // RNE
    return (unsigned short)r;
}
__device__ __forceinline__ unsigned pack2(float a, float b){
    return (unsigned)f2bf(a) | ((unsigned)f2bf(b) << 16);
}

// ---------------- K1: build VA (bf16) in MFMA A-fragment order, zero-padded ----
// granule gid = (kblk*32 + mblk)*64 + lane ; 16B per granule (8 bf16, contiguous k)
// element: A[m = mblk*16 + (lane&15)][k = kblk*32 + (lane>>4)*8 + j]
__global__ void build_af(const float* __restrict__ audio,
                         const float* __restrict__ video,
                         uint4* __restrict__ af)
{
    int gid = blockIdx.x * 256 + threadIdx.x;
    if (gid >= KBLKS * MBLKS * 64) return;
    int lane = gid & 63;
    int mblk = (gid >> 6) & 31;
    int kblk = gid >> 11;
    int m  = mblk * 16 + (lane & 15);
    int k0 = kblk * 32 + (lane >> 4) * 8;
    float vals[8];
#pragma unroll
    for (int j = 0; j < 8; ++j){
        int k = k0 + j;
        float p = 0.f;
        if (k < NJK){
            int jj = k / 65;
            int kk = k - jj * 65;
            float a = (kk == 0) ? 1.f : audio[m * 64 + kk - 1];
            float v = (jj == 0) ? 1.f : video[m * 64 + jj - 1];
            p = a * v;
        }
        vals[j] = p;
    }
    uint4 o;
    o.x = pack2(vals[0], vals[1]);
    o.y = pack2(vals[2], vals[3]);
    o.z = pack2(vals[4], vals[5]);
    o.w = pack2(vals[6], vals[7]);
    af[gid] = o;
}

// ---------------- K2: Z = VA @ W1'  (bf16 MFMA, fused fp32->bf16 W staging) ----
// grid 516 = 4 m-tiles x 129 n-tiles, block 256 (4 waves, 2x2 of 64x64 subtiles)
__global__ __launch_bounds__(256, 2) void fusion_gemm(
    const float* __restrict__ W1,
    const uint4* __restrict__ af,
    float* __restrict__ Z)
{
    __shared__ __align__(16) char smem[128 * 64 * 2];  // Blds[n][k] bf16, XOR-swizzled

    // bijective XCD swizzle (nwg=516: q=64, r=4) -> 4 m-tiles of one n-tile stay on one XCD
    int orig = blockIdx.x;
    int xcd  = orig & 7;
    int base = (xcd < 4) ? xcd * 65 : 260 + (xcd - 4) * 64;
    int w    = base + (orig >> 3);
    int nt = w >> 2;          // 0..128  (column-tile == index i of t1)
    int mt = w & 3;           // 0..3

    int t    = threadIdx.x;
    int lane = t & 63;
    int wv   = t >> 6;
    int wm   = wv >> 1, wn = wv & 1;

    f32x4 acc[4][4] = {};

    int n_loc = t & 127;          // staging: this thread's column
    int kc0   = t >> 7;           // 0/1
    const float* wbase = W1 + (size_t)nt * NJK * 128 + n_loc;

    for (int ks = 0; ks < KPAD / 64; ++ks){
        if (ks) __syncthreads();
        // ---- stage B tile: global fp32 [64k][128n] -> bf16 Blds[n][k] (swizzled)
        if (ks < 66){
#pragma unroll
            for (int c = 0; c < 4; ++c){
                int kc = c * 2 + kc0;
                int kb = ks * 64 + kc * 8;
                float v[8];
#pragma unroll
                for (int j = 0; j < 8; ++j)
                    v[j] = wbase[(size_t)(kb + j) * 128];
                uint4 u;
                u.x = pack2(v[0], v[1]);
                u.y = pack2(v[2], v[3]);
                u.z = pack2(v[4], v[5]);
                u.w = pack2(v[6], v[7]);
                int byte = (n_loc * 128 + kc * 16) ^ ((n_loc & 7) << 4);
                *(uint4*)(smem + byte) = u;
            }
        } else {   // K tail: only k=4224 is real
#pragma unroll
            for (int c = 0; c < 4; ++c){
                int kc = c * 2 + kc0;
                int kb = ks * 64 + kc * 8;
                float v[8];
#pragma unroll
                for (int j = 0; j < 8; ++j){
                    int k = kb + j;
                    v[j] = (k < NJK) ? wbase[(size_t)k * 128] : 0.f;
                }
                uint4 u;
                u.x = pack2(v[0], v[1]);
                u.y = pack2(v[2], v[3]);
                u.z = pack2(v[4], v[5]);
                u.w = pack2(v[6], v[7]);
                int byte = (n_loc * 128 + kc * 16) ^ ((n_loc & 7) << 4);
                *(uint4*)(smem + byte) = u;
            }
        }
        __syncthreads();

        // ---- compute
#pragma unroll
        for (int s = 0; s < 2; ++s){
            int kblk = ks * 2 + s;
            bf16x8 a[4], b[4];
#pragma unroll
            for (int f = 0; f < 4; ++f){
                int mblk = mt * 8 + wm * 4 + f;
                a[f] = *(const bf16x8*)(af + (size_t)(kblk * 32 + mblk) * 64 + lane);
            }
#pragma unroll
            for (int g = 0; g < 4; ++g){
                int nr = wn * 64 + g * 16 + (lane & 15);
                int byte = (nr * 128 + s * 64 + (lane >> 4) * 16) ^ ((nr & 7) << 4);
                b[g] = *(const bf16x8*)(smem + byte);
            }
#pragma unroll
            for (int f = 0; f < 4; ++f)
#pragma unroll
                for (int g = 0; g < 4; ++g)
                    acc[f][g] = __builtin_amdgcn_mfma_f32_16x16x32_bf16(a[f], b[g], acc[f][g], 0, 0, 0);
        }
    }

    // ---- epilogue: Z[m][n], D layout col=lane&15, row=(lane>>4)*4+reg
    int row0 = mt * 128 + wm * 64 + (lane >> 4) * 4;
    int col0 = nt * 128 + wn * 64 + (lane & 15);
#pragma unroll
    for (int f = 0; f < 4; ++f)
#pragma unroll
        for (int g = 0; g < 4; ++g)
#pragma unroll
            for (int r = 0; r < 4; ++r)
                Z[(size_t)(row0 + f * 16 + r) * NTOT + col0 + g * 16] = acc[f][g][r];
}

// ---------------- K3: y1 = relu(b1 + sum_i t1_i * Z[:,i,:]); y2; sigmoid head ---
__global__ void tail_mlp(const float* __restrict__ Z,
                         const float* __restrict__ text,
                         const float* __restrict__ b1,
                         const float* __restrict__ W2,
                         const float* __restrict__ b2,
                         const float* __restrict__ W3,
                         const float* __restrict__ b3,
                         float* __restrict__ out)
{
    int b   = blockIdx.x;     // 512
    int tid = threadIdx.x;    // 128
    __shared__ float t1s[NI];
    __shared__ float y1s[POST];
    __shared__ float red[2];

    t1s[tid + 1] = text[b * 128 + tid];
    if (tid == 0) t1s[0] = 1.f;
    __syncthreads();

    const float* zrow = Z + (size_t)b * NTOT;
    float acc = 0.f;
    for (int i = 0; i < NI; ++i)
        acc = fmaf(t1s[i], zrow[i * 128 + tid], acc);
    acc += b1[tid];
    float y1 = fmaxf(acc, 0.f);
    y1s[tid] = y1;
    __syncthreads();

    float a2 = b2[tid];
    for (int q = 0; q < 128; ++q)
        a2 = fmaf(y1s[q], W2[q * 128 + tid], a2);
    float y2 = fmaxf(a2, 0.f);

    float part = y2 * W3[tid];
#pragma unroll
    for (int off = 32; off > 0; off >>= 1)
        part += __shfl_down(part, off);
    if ((tid & 63) == 0) red[tid >> 6] = part;
    __syncthreads();
    if (tid == 0){
        float z = red[0] + red[1] + b3[0];
        out[b] = 6.f / (1.f + expf(-z)) - 3.f;
    }
}

extern "C" void kernel_launch(void* const* d_in, const int* in_sizes, int n_in,
                              void* d_out, int out_size, void* d_ws, size_t ws_size,
                              hipStream_t stream)
{
    const float* audio = (const float*)d_in[0];
    const float* video = (const float*)d_in[1];
    const float* text  = (const float*)d_in[2];
    const float* W1    = (const float*)d_in[3];
    const float* b1    = (const float*)d_in[4];
    const float* W2    = (const float*)d_in[5];
    const float* b2    = (const float*)d_in[6];
    const float* W3    = (const float*)d_in[7];
    const float* b3    = (const float*)d_in[8];
    float* out = (float*)d_out;

    char* ws = (char*)d_ws;
    uint4* af = (uint4*)ws;                       // 4,390,912 B (A fragments, bf16)
    float* Z  = (float*)(ws + (8u << 20));        // 33,816,576 B

    int af_granules = KBLKS * MBLKS * 64;         // 274432
    build_af<<<(af_granules + 255) / 256, 256, 0, stream>>>(audio, video, af);
    fusion_gemm<<<516, 256, 0, stream>>>(W1, af, Z);
    tail_mlp<<<512, 128, 0, stream>>>(Z, text, b1, W2, b2, W3, b3, out);
}

// Round 2
// 250.800 us; speedup vs baseline: 1.1098x; 1.1098x over previous
//
#include <hip/hip_runtime.h>
#include <hip/hip_bf16.h>
#include <math.h>

#define POST 128
#define NI 129            // T+1
#define NJK 4225          // 65*65
#define KPAD 4288         // 67*64
#define NTOT 16512        // 129*128
#define KBLKS 134         // KPAD/32
#define MBLKS 32          // 512/16
#define KSTEPS 67         // KPAD/64

typedef __attribute__((ext_vector_type(8))) short bf16x8;
typedef __attribute__((ext_vector_type(4))) float f32x4;

__device__ __forceinline__ unsigned short f2bf(float f){
    unsigned u = __builtin_bit_cast(unsigned, f);
    unsigned r = (u + 0x7FFFu + ((u >> 16) & 1u)) >> 16;   // RNE
    return (unsigned short)r;
}
__device__ __forceinline__ unsigned pack2(float a, float b){
    return (unsigned)f2bf(a) | ((unsigned)f2bf(b) << 16);
}

// ---------------- K1: build VA (bf16) in MFMA A-fragment order, zero-padded ----
// granule gid = (kblk*32 + mblk)*64 + lane ; 16B per granule (8 bf16, contiguous k)
// element: A[m = mblk*16 + (lane&15)][k = kblk*32 + (lane>>4)*8 + j]
__global__ void build_af(const float* __restrict__ audio,
                         const float* __restrict__ video,
                         uint4* __restrict__ af)
{
    int gid = blockIdx.x * 256 + threadIdx.x;
    if (gid >= KBLKS * MBLKS * 64) return;
    int lane = gid & 63;
    int mblk = (gid >> 6) & 31;
    int kblk = gid >> 11;
    int m  = mblk * 16 + (lane & 15);
    int k0 = kblk * 32 + (lane >> 4) * 8;
    float vals[8];
#pragma unroll
    for (int j = 0; j < 8; ++j){
        int k = k0 + j;
        float p = 0.f;
        if (k < NJK){
            int jj = k / 65;
            int kk = k - jj * 65;
            float a = (kk == 0) ? 1.f : audio[m * 64 + kk - 1];
            float v = (jj == 0) ? 1.f : video[m * 64 + jj - 1];
            p = a * v;
        }
        vals[j] = p;
    }
    uint4 o;
    o.x = pack2(vals[0], vals[1]);
    o.y = pack2(vals[2], vals[3]);
    o.z = pack2(vals[4], vals[5]);
    o.w = pack2(vals[6], vals[7]);
    af[gid] = o;
}

// ---------------- K2: Z = VA @ W1'  (bf16 MFMA, dbuf LDS + T14 async staging) --
// grid 1032 = 8 m-tiles x 129 n-tiles, block 256 (4 waves, 2x2 of 32x64 subtiles)
__global__ __launch_bounds__(256, 4) void fusion_gemm(
    const float* __restrict__ W1,
    const uint4* __restrict__ af,
    float* __restrict__ Z)
{
    __shared__ __align__(16) char smem[2][128 * 64 * 2];  // Blds[n][k] bf16, XOR-swizzled

    // bijective XCD swizzle (nwg=1032, 1032%8==0): all 8 mt of one nt on one XCD
    int orig = blockIdx.x;
    int xcd  = orig & 7;
    int w    = xcd * 129 + (orig >> 3);
    int nt = w >> 3;          // 0..128  (column-tile == index i of t1)
    int mt = w & 7;           // 0..7

    int t    = threadIdx.x;
    int lane = t & 63;
    int wv   = t >> 6;
    int wm   = wv >> 1, wn = wv & 1;

    f32x4 acc[2][4] = {};

    int n_loc = t & 127;          // staging: this thread's column of W1
    int kg    = t >> 7;           // 0/1
    const float* wbase = W1 + (size_t)nt * (NJK * 128) + n_loc;

    float v[4][8];                // staged fp32 W1 values (next tile)
    bf16x8 a_cur0, a_cur1, a_cur2, a_cur3;   // A frags [s][f] for current tile
    bf16x8 a_nxt0, a_nxt1, a_nxt2, a_nxt3;

    const int mb0 = mt * 4 + wm * 2;

#define LOADW(ks_)                                                              \
    do {                                                                        \
        int kb_ = (ks_) * 64;                                                   \
        if ((ks_) < KSTEPS - 1) {                                               \
            _Pragma("unroll")                                                   \
            for (int c = 0; c < 4; ++c){                                        \
                int k0_ = kb_ + (c * 2 + kg) * 8;                               \
                _Pragma("unroll")                                               \
                for (int j = 0; j < 8; ++j)                                     \
                    v[c][j] = wbase[(size_t)(k0_ + j) * 128];                   \
            }                                                                   \
        } else {                                                                \
            _Pragma("unroll")                                                   \
            for (int c = 0; c < 4; ++c){                                        \
                int k0_ = kb_ + (c * 2 + kg) * 8;                               \
                _Pragma("unroll")                                               \
                for (int j = 0; j < 8; ++j){                                    \
                    int k_ = k0_ + j;                                           \
                    v[c][j] = (k_ < NJK) ? wbase[(size_t)k_ * 128] : 0.f;       \
                }                                                               \
            }                                                                   \
        }                                                                       \
    } while (0)

#define WRITEW(buf_)                                                            \
    do {                                                                        \
        _Pragma("unroll")                                                       \
        for (int c = 0; c < 4; ++c){                                            \
            int kc_ = c * 2 + kg;                                               \
            uint4 u_;                                                           \
            u_.x = pack2(v[c][0], v[c][1]);                                     \
            u_.y = pack2(v[c][2], v[c][3]);                                     \
            u_.z = pack2(v[c][4], v[c][5]);                                     \
            u_.w = pack2(v[c][6], v[c][7]);                                     \
            int byte_ = (n_loc * 128 + kc_ * 16) ^ ((n_loc & 7) << 4);          \
            *(uint4*)(smem[buf_] + byte_) = u_;                                 \
        }                                                                       \
    } while (0)

#define LOADA(ks_, d0, d1, d2, d3)                                              \
    do {                                                                        \
        int kb_ = (ks_) * 2;                                                    \
        d0 = *(const bf16x8*)(af + ((size_t)((kb_    ) * 32 + mb0    )) * 64 + lane); \
        d1 = *(const bf16x8*)(af + ((size_t)((kb_    ) * 32 + mb0 + 1)) * 64 + lane); \
        d2 = *(const bf16x8*)(af + ((size_t)((kb_ + 1) * 32 + mb0    )) * 64 + lane); \
        d3 = *(const bf16x8*)(af + ((size_t)((kb_ + 1) * 32 + mb0 + 1)) * 64 + lane); \
    } while (0)

    // prologue
    LOADW(0);
    LOADA(0, a_cur0, a_cur1, a_cur2, a_cur3);
    WRITEW(0);
    __syncthreads();

    for (int ks = 0; ks < KSTEPS; ++ks){
        int nxt = ks + 1;
        if (nxt < KSTEPS){
            LOADW(nxt);                                   // issue early (T14)
            LOADA(nxt, a_nxt0, a_nxt1, a_nxt2, a_nxt3);
        }

        // ---- compute from smem[ks&1]
        const char* sb = smem[ks & 1];
        int nr_base = wn * 64 + (lane & 15);
        int koff    = (lane >> 4) * 16;
#pragma unroll
        for (int s = 0; s < 2; ++s){
            bf16x8 b[4];
#pragma unroll
            for (int g = 0; g < 4; ++g){
                int nr = nr_base + g * 16;
                int byte = (nr * 128 + s * 64 + koff) ^ ((nr & 7) << 4);
                b[g] = *(const bf16x8*)(sb + byte);
            }
            bf16x8 a0 = s ? a_cur2 : a_cur0;
            bf16x8 a1 = s ? a_cur3 : a_cur1;
#pragma unroll
            for (int g = 0; g < 4; ++g){
                acc[0][g] = __builtin_amdgcn_mfma_f32_16x16x32_bf16(a0, b[g], acc[0][g], 0, 0, 0);
                acc[1][g] = __builtin_amdgcn_mfma_f32_16x16x32_bf16(a1, b[g], acc[1][g], 0, 0, 0);
            }
        }

        if (nxt < KSTEPS){
            WRITEW(nxt & 1);                              // waits vmcnt as needed
            a_cur0 = a_nxt0; a_cur1 = a_nxt1; a_cur2 = a_nxt2; a_cur3 = a_nxt3;
        }
        __syncthreads();
    }

    // ---- epilogue: Z[m][n], D layout col=lane&15, row=(lane>>4)*4+reg
    int row0 = mt * 64 + wm * 32 + (lane >> 4) * 4;
    int col0 = nt * 128 + wn * 64 + (lane & 15);
#pragma unroll
    for (int f = 0; f < 2; ++f)
#pragma unroll
        for (int g = 0; g < 4; ++g)
#pragma unroll
            for (int r = 0; r < 4; ++r)
                Z[(size_t)(row0 + f * 16 + r) * NTOT + col0 + g * 16] = acc[f][g][r];
}

// ---------------- K3: y1 = relu(b1 + sum_i t1_i * Z[:,i,:]); y2; sigmoid head ---
__global__ void tail_mlp(const float* __restrict__ Z,
                         const float* __restrict__ text,
                         const float* __restrict__ b1,
                         const float* __restrict__ W2,
                         const float* __restrict__ b2,
                         const float* __restrict__ W3,
                         const float* __restrict__ b3,
                         float* __restrict__ out)
{
    int b   = blockIdx.x;     // 512
    int tid = threadIdx.x;    // 128
    __shared__ float t1s[NI];
    __shared__ float y1s[POST];
    __shared__ float red[2];

    t1s[tid + 1] = text[b * 128 + tid];
    if (tid == 0) t1s[0] = 1.f;
    __syncthreads();

    const float* zrow = Z + (size_t)b * NTOT;
    float acc = 0.f;
    for (int i = 0; i < NI; ++i)
        acc = fmaf(t1s[i], zrow[i * 128 + tid], acc);
    acc += b1[tid];
    float y1 = fmaxf(acc, 0.f);
    y1s[tid] = y1;
    __syncthreads();

    float a2 = b2[tid];
    for (int q = 0; q < 128; ++q)
        a2 = fmaf(y1s[q], W2[q * 128 + tid], a2);
    float y2 = fmaxf(a2, 0.f);

    float part = y2 * W3[tid];
#pragma unroll
    for (int off = 32; off > 0; off >>= 1)
        part += __shfl_down(part, off);
    if ((tid & 63) == 0) red[tid >> 6] = part;
    __syncthreads();
    if (tid == 0){
        float z = red[0] + red[1] + b3[0];
        out[b] = 6.f / (1.f + expf(-z)) - 3.f;
    }
}

extern "C" void kernel_launch(void* const* d_in, const int* in_sizes, int n_in,
                              void* d_out, int out_size, void* d_ws, size_t ws_size,
                              hipStream_t stream)
{
    const float* audio = (const float*)d_in[0];
    const float* video = (const float*)d_in[1];
    const float* text  = (const float*)d_in[2];
    const float* W1    = (const float*)d_in[3];
    const float* b1    = (const float*)d_in[4];
    const float* W2    = (const float*)d_in[5];
    const float* b2    = (const float*)d_in[6];
    const float* W3    = (const float*)d_in[7];
    const float* b3    = (const float*)d_in[8];
    float* out = (float*)d_out;

    char* ws = (char*)d_ws;
    uint4* af = (uint4*)ws;                       // 4,390,912 B (A fragments, bf16)
    float* Z  = (float*)(ws + (8u << 20));        // 33,816,576 B

    int af_granules = KBLKS * MBLKS * 64;         // 274432
    build_af<<<(af_granules + 255) / 256, 256, 0, stream>>>(audio, video, af);
    fusion_gemm<<<1032, 256, 0, stream>>>(W1, af, Z);
    tail_mlp<<<512, 128, 0, stream>>>(Z, text, b1, W2, b2, W3, b3, out);
}

// Round 3
// 232.010 us; speedup vs baseline: 1.1997x; 1.0810x over previous
//
#include <hip/hip_runtime.h>
#include <hip/hip_bf16.h>
#include <math.h>

#define POST 128
#define NI 129            // T+1
#define NJK 4225          // 65*65
#define KPAD 4288         // 67*64
#define NTOT 16512        // 129*128
#define KBLKS 134         // KPAD/32 (k-blocks of 32)
#define MBLKS 32          // 512/16
#define KSTEPS 67         // KPAD/64
#define NGRAN (129*KBLKS*8)   // 138288 B-granules

typedef __attribute__((ext_vector_type(8))) short bf16x8;
typedef __attribute__((ext_vector_type(4))) float f32x4;

__device__ __forceinline__ unsigned short f2bf(float f){
    unsigned u = __builtin_bit_cast(unsigned, f);
    unsigned r = (u + 0x7FFFu + ((u >> 16) & 1u)) >> 16;   // RNE
    return (unsigned short)r;
}
__device__ __forceinline__ unsigned pack2(float a, float b){
    return (unsigned)f2bf(a) | ((unsigned)f2bf(b) << 16);
}

__device__ __forceinline__ void gload16(const void* g, void* l){
    __builtin_amdgcn_global_load_lds(
        (const __attribute__((address_space(1))) unsigned int*)g,
        (__attribute__((address_space(3))) unsigned int*)l, 16, 0, 0);
}

// ---------------- K1: build VA (bf16) in MFMA A-fragment granule order --------
// granule (kblk, mblk): 64 lanes x 16B; element (l,j): m=mblk*16+(l&15),
// k = kblk*32 + (l>>4)*8 + j. Zero-padded past NJK.
__global__ void build_af(const float* __restrict__ audio,
                         const float* __restrict__ video,
                         uint4* __restrict__ af)
{
    int gid = blockIdx.x * 256 + threadIdx.x;
    if (gid >= KBLKS * MBLKS * 64) return;
    int lane = gid & 63;
    int mblk = (gid >> 6) & 31;
    int kblk = gid >> 11;
    int m  = mblk * 16 + (lane & 15);
    int k0 = kblk * 32 + (lane >> 4) * 8;
    float vals[8];
#pragma unroll
    for (int j = 0; j < 8; ++j){
        int k = k0 + j;
        float p = 0.f;
        if (k < NJK){
            int jj = k / 65;
            int kk = k - jj * 65;
            float a = (kk == 0) ? 1.f : audio[m * 64 + kk - 1];
            float v = (jj == 0) ? 1.f : video[m * 64 + jj - 1];
            p = a * v;
        }
        vals[j] = p;
    }
    uint4 o;
    o.x = pack2(vals[0], vals[1]);
    o.y = pack2(vals[2], vals[3]);
    o.z = pack2(vals[4], vals[5]);
    o.w = pack2(vals[6], vals[7]);
    af[gid] = o;
}

// ---------------- K2: convert W1 fp32 -> bf16 in B-fragment granule order -----
// granule g = (nt*KBLKS + kblk)*8 + ng : 64 lanes x 16B; element (l,j):
// n = ng*16 + (l&15), k = kblk*32 + (l>>4)*8 + j  (zero past NJK)
__global__ void convert_w1(const float* __restrict__ W1, uint4* __restrict__ w1b)
{
    int gid = blockIdx.x * 256 + threadIdx.x;
    if (gid >= NGRAN * 64) return;
    int lane = gid & 63;
    int g    = gid >> 6;
    int ng   = g & 7;
    int tk   = g >> 3;               // nt*KBLKS + kblk
    int kblk = tk % KBLKS;
    int nt   = tk / KBLKS;
    int n    = ng * 16 + (lane & 15);
    int k0   = kblk * 32 + (lane >> 4) * 8;
    const float* src = W1 + (size_t)nt * NJK * 128 + n;
    float v[8];
#pragma unroll
    for (int j = 0; j < 8; ++j){
        int k = k0 + j;
        v[j] = (k < NJK) ? src[(size_t)k * 128] : 0.f;
    }
    uint4 o;
    o.x = pack2(v[0], v[1]);
    o.y = pack2(v[2], v[3]);
    o.z = pack2(v[4], v[5]);
    o.w = pack2(v[6], v[7]);
    w1b[(size_t)g * 64 + lane] = o;
}

// ---------------- K3: Z = VA @ W1'  (m97 structure: gload_lds + dbuf LDS) -----
// 128x128 tile, BK=64, grid 516 = 4 mt x 129 nt, 4 waves (2x2 of 64x64)
__global__ __launch_bounds__(256, 2) void fusion_gemm(
    const uint4* __restrict__ af,
    const uint4* __restrict__ w1b,
    float* __restrict__ Z)
{
    // LDS per buffer: [A s=0 8K][A s=1 8K][B s=0 8K][B s=1 8K] = 32KB, granule-linear
    __shared__ __align__(16) char smem[2][32768];

    // bijective XCD swizzle (nwg=516: q=64, r=4)
    int orig = blockIdx.x;
    int xcd  = orig & 7;
    int base = (xcd < 4) ? xcd * 65 : 260 + (xcd - 4) * 64;
    int w    = base + (orig >> 3);
    int nt = w >> 2;          // 0..128
    int mt = w & 3;           // 0..3

    int t    = threadIdx.x;
    int lane = t & 63;
    int wv   = t >> 6;
    int wm   = wv >> 1, wn = wv & 1;

    f32x4 acc[4][4] = {};

    // staging: wave wv owns one 8KB chunk: wv=0,1 -> A s=wv ; wv=2,3 -> B s=wv-2
    const uint4* chunk_src0 = (wv < 2) ? af : w1b;
    char* dst_base0 = nullptr;  // set per buf

#define STAGE(ks_, buf_)                                                        \
    do {                                                                        \
        size_t gidx_;                                                           \
        if (wv < 2) gidx_ = ((size_t)((2*(ks_) + wv) * 32 + mt * 8)) * 64;      \
        else        gidx_ = ((size_t)((nt * KBLKS + 2*(ks_) + (wv-2)) * 8)) * 64;\
        const uint4* src_ = chunk_src0 + gidx_ + lane;                          \
        char* dst_ = smem[buf_] + wv * 8192;                                    \
        _Pragma("unroll")                                                       \
        for (int c_ = 0; c_ < 8; ++c_)                                          \
            gload16(src_ + c_ * 64, dst_ + c_ * 1024);                          \
    } while (0)

    STAGE(0, 0);
    __syncthreads();

    for (int ks = 0; ks < KSTEPS; ++ks){
        if (ks < KSTEPS - 1) STAGE(ks + 1, (ks + 1) & 1);

        const char* sb = smem[ks & 1];
#pragma unroll
        for (int s = 0; s < 2; ++s){
            bf16x8 a[4], b[4];
#pragma unroll
            for (int f = 0; f < 4; ++f)
                a[f] = *(const bf16x8*)(sb + s * 8192 + (wm * 4 + f) * 1024 + lane * 16);
#pragma unroll
            for (int g = 0; g < 4; ++g)
                b[g] = *(const bf16x8*)(sb + 16384 + s * 8192 + (wn * 4 + g) * 1024 + lane * 16);
#pragma unroll
            for (int f = 0; f < 4; ++f)
#pragma unroll
                for (int g = 0; g < 4; ++g)
                    acc[f][g] = __builtin_amdgcn_mfma_f32_16x16x32_bf16(a[f], b[g], acc[f][g], 0, 0, 0);
        }
        __syncthreads();
    }

    // epilogue: D layout col=lane&15, row=(lane>>4)*4+reg
    int row0 = mt * 128 + wm * 64 + (lane >> 4) * 4;
    int col0 = nt * 128 + wn * 64 + (lane & 15);
#pragma unroll
    for (int f = 0; f < 4; ++f)
#pragma unroll
        for (int g = 0; g < 4; ++g)
#pragma unroll
            for (int r = 0; r < 4; ++r)
                Z[(size_t)(row0 + f * 16 + r) * NTOT + col0 + g * 16] = acc[f][g][r];
}

// ---------------- K4: y1 = relu(b1 + sum_i t1_i * Z[:,i,:]); y2; sigmoid head --
__global__ void tail_mlp(const float* __restrict__ Z,
                         const float* __restrict__ text,
                         const float* __restrict__ b1,
                         const float* __restrict__ W2,
                         const float* __restrict__ b2,
                         const float* __restrict__ W3,
                         const float* __restrict__ b3,
                         float* __restrict__ out)
{
    int b   = blockIdx.x;     // 512
    int tid = threadIdx.x;    // 128
    __shared__ float t1s[NI];
    __shared__ float y1s[POST];
    __shared__ float red[2];

    t1s[tid + 1] = text[b * 128 + tid];
    if (tid == 0) t1s[0] = 1.f;
    __syncthreads();

    const float* zrow = Z + (size_t)b * NTOT;
    float acc = 0.f;
    for (int i = 0; i < NI; ++i)
        acc = fmaf(t1s[i], zrow[i * 128 + tid], acc);
    acc += b1[tid];
    float y1 = fmaxf(acc, 0.f);
    y1s[tid] = y1;
    __syncthreads();

    float a2 = b2[tid];
    for (int q = 0; q < 128; ++q)
        a2 = fmaf(y1s[q], W2[q * 128 + tid], a2);
    float y2 = fmaxf(a2, 0.f);

    float part = y2 * W3[tid];
#pragma unroll
    for (int off = 32; off > 0; off >>= 1)
        part += __shfl_down(part, off);
    if ((tid & 63) == 0) red[tid >> 6] = part;
    __syncthreads();
    if (tid == 0){
        float z = red[0] + red[1] + b3[0];
        out[b] = 6.f / (1.f + expf(-z)) - 3.f;
    }
}

extern "C" void kernel_launch(void* const* d_in, const int* in_sizes, int n_in,
                              void* d_out, int out_size, void* d_ws, size_t ws_size,
                              hipStream_t stream)
{
    const float* audio = (const float*)d_in[0];
    const float* video = (const float*)d_in[1];
    const float* text  = (const float*)d_in[2];
    const float* W1    = (const float*)d_in[3];
    const float* b1    = (const float*)d_in[4];
    const float* W2    = (const float*)d_in[5];
    const float* b2    = (const float*)d_in[6];
    const float* W3    = (const float*)d_in[7];
    const float* b3    = (const float*)d_in[8];
    float* out = (float*)d_out;

    char* ws = (char*)d_ws;
    uint4* af  = (uint4*)ws;                      // 4,390,912 B
    float* Z   = (float*)(ws + (5u << 20));       // 33,816,576 B
    uint4* w1b = (uint4*)(ws + (40u << 20));      // 141,606,912 B

    int af_granules = KBLKS * MBLKS * 64;         // 274432 threads
    build_af<<<(af_granules + 255) / 256, 256, 0, stream>>>(audio, video, af);
    convert_w1<<<(NGRAN * 64 + 255) / 256, 256, 0, stream>>>(W1, w1b);
    fusion_gemm<<<516, 256, 0, stream>>>(af, w1b, Z);
    tail_mlp<<<512, 128, 0, stream>>>(Z, text, b1, W2, b2, W3, b3, out);
}

// Round 5
// 200.452 us; speedup vs baseline: 1.3886x; 1.1574x over previous
//
#include <hip/hip_runtime.h>
#include <hip/hip_bf16.h>
#include <math.h>

#define POST 128
#define NI 129            // T+1
#define NJK 4225          // 65*65
#define KPAD 4288         // 67*64
#define NTOT 16512        // 129*128
#define KBLKS 134         // KPAD/32 (k-blocks of 32)
#define MBLKS 32          // 512/16
#define KSTEPS 67         // KPAD/64

typedef __attribute__((ext_vector_type(8))) short bf16x8;
typedef __attribute__((ext_vector_type(4))) float f32x4;
typedef __attribute__((ext_vector_type(4))) unsigned int u32x4;

__device__ __forceinline__ unsigned short f2bf(float f){
    unsigned u = __builtin_bit_cast(unsigned, f);
    unsigned r = (u + 0x7FFFu + ((u >> 16) & 1u)) >> 16;   // RNE
    return (unsigned short)r;
}
__device__ __forceinline__ unsigned pack2(float a, float b){
    return (unsigned)f2bf(a) | ((unsigned)f2bf(b) << 16);
}

// ---------------- K1: build VA (bf16) in MFMA A-fragment granule order --------
// granule (kblk, mblk): 64 lanes x 16B; element (l,j): m=mblk*16+(l&15),
// k = kblk*32 + (l>>4)*8 + j. Zero-padded past NJK.
__global__ void build_af(const float* __restrict__ audio,
                         const float* __restrict__ video,
                         uint4* __restrict__ af)
{
    int gid = blockIdx.x * 256 + threadIdx.x;
    if (gid >= KBLKS * MBLKS * 64) return;
    int lane = gid & 63;
    int mblk = (gid >> 6) & 31;
    int kblk = gid >> 11;
    int m  = mblk * 16 + (lane & 15);
    int k0 = kblk * 32 + (lane >> 4) * 8;
    float vals[8];
#pragma unroll
    for (int j = 0; j < 8; ++j){
        int k = k0 + j;
        float p = 0.f;
        if (k < NJK){
            int jj = k / 65;
            int kk = k - jj * 65;
            float a = (kk == 0) ? 1.f : audio[m * 64 + kk - 1];
            float v = (jj == 0) ? 1.f : video[m * 64 + jj - 1];
            p = a * v;
        }
        vals[j] = p;
    }
    uint4 o;
    o.x = pack2(vals[0], vals[1]);
    o.y = pack2(vals[2], vals[3]);
    o.z = pack2(vals[4], vals[5]);
    o.w = pack2(vals[6], vals[7]);
    af[gid] = o;
}

// ---------------- K2: fused Z = VA @ bf16(W1')  -------------------------------
// 128x128 tile, BK=64, grid 516 = 4 mt x 129 nt, 4 waves (2x2 of 64x64).
// B: fp32 global (coalesced, imm-offset rows) -> RNE cvt in reg ->
//    ds_write_b128 into [n][k] bf16 layout with XOR swizzle ((n&7)<<4)  [R1/R2-proven]
// A: reg-staged uint4 from af granules -> linear LDS.
// Double-buffered; reg-prefetch next tile before compute (T14), one barrier/iter.
__global__ __launch_bounds__(256, 2) void fusion_gemm(
    const float* __restrict__ W1,
    const uint4* __restrict__ af,
    float* __restrict__ Z)
{
    __shared__ __align__(16) char lds[65536];
    // [0,16K) A buf0 | [16K,32K) A buf1 | [32K,48K) B buf0 | [48K,64K) B buf1

    // bijective XCD swizzle (nwg=516: q=64, r=4): 4 mt of one nt stay adjacent
    int orig = blockIdx.x;
    int xcd  = orig & 7;
    int base = (xcd < 4) ? xcd * 65 : 260 + (xcd - 4) * 64;
    int w    = base + (orig >> 3);
    int nt = w >> 2;          // 0..128
    int mt = w & 3;           // 0..3

    int t    = threadIdx.x;
    int lane = t & 63;
    int wv   = t >> 6;
    int wm   = wv >> 1, wn = wv & 1;

    f32x4 acc[4][4] = {};

    const float* wpanel = W1 + (size_t)nt * (NJK * 128);

    // B staging: thread covers n in {nb, nb+64}, k rows kg*8..kg*8+7 (+c*32)
    int nb = t & 63;
    int kg = t >> 6;          // == wv (wave-uniform)

    float vB[2][2][8];        // [c][half][j]
    uint4 vA[4];

#define BLOAD(ks_)                                                          \
    do {                                                                    \
        if ((ks_) == KSTEPS - 1) {                                          \
            _Pragma("unroll")                                               \
            for (int c = 0; c < 2; ++c){                                    \
                int kr0 = (ks_) * 64 + c * 32 + kg * 8;                     \
                _Pragma("unroll")                                           \
                for (int j = 0; j < 8; ++j){                                \
                    int kr = kr0 + j; kr = kr < 4224 ? kr : 4224;           \
                    vB[c][0][j] = wpanel[(size_t)kr * 128 + nb];            \
                    vB[c][1][j] = wpanel[(size_t)kr * 128 + nb + 64];       \
                }                                                           \
            }                                                               \
        } else {                                                            \
            _Pragma("unroll")                                               \
            for (int c = 0; c < 2; ++c){                                    \
                const float* wr = wpanel + (size_t)((ks_) * 64 + c * 32 + kg * 8) * 128 + nb; \
                _Pragma("unroll")                                           \
                for (int j = 0; j < 8; ++j){                                \
                    vB[c][0][j] = wr[j * 128];                              \
                    vB[c][1][j] = wr[j * 128 + 64];                         \
                }                                                           \
            }                                                               \
        }                                                                   \
    } while (0)

#define BWRITE(buf_)                                                        \
    do {                                                                    \
        char* dstb_ = lds + 32768 + (buf_) * 16384;                         \
        _Pragma("unroll")                                                   \
        for (int c = 0; c < 2; ++c){                                        \
            _Pragma("unroll")                                               \
            for (int h = 0; h < 2; ++h){                                    \
                int n_ = nb + h * 64;                                       \
                u32x4 u_;                                                   \
                u_.x = pack2(vB[c][h][0], vB[c][h][1]);                     \
                u_.y = pack2(vB[c][h][2], vB[c][h][3]);                     \
                u_.z = pack2(vB[c][h][4], vB[c][h][5]);                     \
                u_.w = pack2(vB[c][h][6], vB[c][h][7]);                     \
                int byte_ = (n_ * 128 + c * 64 + kg * 16) ^ ((n_ & 7) << 4);\
                *(u32x4*)(dstb_ + byte_) = u_;                              \
            }                                                               \
        }                                                                   \
    } while (0)

#define ALOAD(ks_)                                                          \
    do {                                                                    \
        _Pragma("unroll")                                                   \
        for (int c = 0; c < 4; ++c){                                        \
            int g_ = wv + c * 4;                                            \
            int kblk_ = 2 * (ks_) + (g_ >> 3);                              \
            vA[c] = af[(size_t)(kblk_ * 32 + mt * 8 + (g_ & 7)) * 64 + lane]; \
        }                                                                   \
    } while (0)

#define AWRITE(buf_)                                                        \
    do {                                                                    \
        char* dsta_ = lds + (buf_) * 16384;                                 \
        _Pragma("unroll")                                                   \
        for (int c = 0; c < 4; ++c)                                         \
            *(uint4*)(dsta_ + (wv + c * 4) * 1024 + lane * 16) = vA[c];     \
    } while (0)

    // prologue
    BLOAD(0); ALOAD(0);
    AWRITE(0); BWRITE(0);
    __syncthreads();

    for (int ks = 0; ks < KSTEPS; ++ks){
        if (ks < KSTEPS - 1){
            BLOAD(ks + 1);
            ALOAD(ks + 1);
            __builtin_amdgcn_sched_barrier(0);   // pin: loads issue before compute
        }

        // ---- compute from bufs [ks&1]
        {
            const char* sa = lds + (ks & 1) * 16384;
            const char* sb = lds + 32768 + (ks & 1) * 16384;
#pragma unroll
            for (int s = 0; s < 2; ++s){
                bf16x8 a[4], b[4];
#pragma unroll
                for (int f = 0; f < 4; ++f)
                    a[f] = *(const bf16x8*)(sa + (s * 8 + wm * 4 + f) * 1024 + lane * 16);
#pragma unroll
                for (int g = 0; g < 4; ++g){
                    int nr = wn * 64 + g * 16 + (lane & 15);
                    int byte = (nr * 128 + s * 64 + (lane >> 4) * 16) ^ ((nr & 7) << 4);
                    b[g] = *(const bf16x8*)(sb + byte);
                }
#pragma unroll
                for (int f = 0; f < 4; ++f)
#pragma unroll
                    for (int g = 0; g < 4; ++g)
                        acc[f][g] = __builtin_amdgcn_mfma_f32_16x16x32_bf16(a[f], b[g], acc[f][g], 0, 0, 0);
            }
        }

        if (ks < KSTEPS - 1){
            AWRITE((ks + 1) & 1);
            BWRITE((ks + 1) & 1);
        }
        __syncthreads();
    }

    // epilogue: D layout col=lane&15, row=(lane>>4)*4+reg
    int row0 = mt * 128 + wm * 64 + (lane >> 4) * 4;
    int col0 = nt * 128 + wn * 64 + (lane & 15);
#pragma unroll
    for (int f = 0; f < 4; ++f)
#pragma unroll
        for (int g = 0; g < 4; ++g)
#pragma unroll
            for (int r = 0; r < 4; ++r)
                Z[(size_t)(row0 + f * 16 + r) * NTOT + col0 + g * 16] = acc[f][g][r];
}

// ---------------- K3: y1 = relu(b1 + sum_i t1_i * Z[:,i,:]); y2; sigmoid head --
__global__ void tail_mlp(const float* __restrict__ Z,
                         const float* __restrict__ text,
                         const float* __restrict__ b1,
                         const float* __restrict__ W2,
                         const float* __restrict__ b2,
                         const float* __restrict__ W3,
                         const float* __restrict__ b3,
                         float* __restrict__ out)
{
    int b   = blockIdx.x;     // 512
    int tid = threadIdx.x;    // 128
    __shared__ float t1s[NI];
    __shared__ float y1s[POST];
    __shared__ float red[2];

    t1s[tid + 1] = text[b * 128 + tid];
    if (tid == 0) t1s[0] = 1.f;
    __syncthreads();

    const float* zrow = Z + (size_t)b * NTOT;
    float acc = 0.f;
    for (int i = 0; i < NI; ++i)
        acc = fmaf(t1s[i], zrow[i * 128 + tid], acc);
    acc += b1[tid];
    float y1 = fmaxf(acc, 0.f);
    y1s[tid] = y1;
    __syncthreads();

    float a2 = b2[tid];
    for (int q = 0; q < 128; ++q)
        a2 = fmaf(y1s[q], W2[q * 128 + tid], a2);
    float y2 = fmaxf(a2, 0.f);

    float part = y2 * W3[tid];
#pragma unroll
    for (int off = 32; off > 0; off >>= 1)
        part += __shfl_down(part, off);
    if ((tid & 63) == 0) red[tid >> 6] = part;
    __syncthreads();
    if (tid == 0){
        float z = red[0] + red[1] + b3[0];
        out[b] = 6.f / (1.f + expf(-z)) - 3.f;
    }
}

extern "C" void kernel_launch(void* const* d_in, const int* in_sizes, int n_in,
                              void* d_out, int out_size, void* d_ws, size_t ws_size,
                              hipStream_t stream)
{
    const float* audio = (const float*)d_in[0];
    const float* video = (const float*)d_in[1];
    const float* text  = (const float*)d_in[2];
    const float* W1    = (const float*)d_in[3];
    const float* b1    = (const float*)d_in[4];
    const float* W2    = (const float*)d_in[5];
    const float* b2    = (const float*)d_in[6];
    const float* W3    = (const float*)d_in[7];
    const float* b3    = (const float*)d_in[8];
    float* out = (float*)d_out;

    char* ws = (char*)d_ws;
    uint4* af = (uint4*)ws;                       // 4,390,912 B
    float* Z  = (float*)(ws + (8u << 20));        // 33,816,576 B

    int af_granules = KBLKS * MBLKS * 64;         // 274432 threads
    build_af<<<(af_granules + 255) / 256, 256, 0, stream>>>(audio, video, af);
    fusion_gemm<<<516, 256, 0, stream>>>(W1, af, Z);
    tail_mlp<<<512, 128, 0, stream>>>(Z, text, b1, W2, b2, W3, b3, out);
}